// Round 5
// baseline (405.454 us; speedup 1.0000x reference)
//
#include <hip/hip_runtime.h>
#include <hip/hip_bf16.h>

typedef unsigned short u16;
typedef short bf16x8 __attribute__((ext_vector_type(8)));
typedef float f32x4 __attribute__((ext_vector_type(4)));

__device__ __forceinline__ float b2f(u16 u) { return __uint_as_float(((unsigned)u) << 16); }
__device__ __forceinline__ u16 f2b(float f) {
    unsigned x = __float_as_uint(f);
    return (u16)((x + 0x7fffu + ((x >> 16) & 1u)) >> 16);
}

// ---------------- cast: both branches in one launch ----------------
__global__ void cast_x_all(const float* __restrict__ x, const float* __restrict__ wtx,
                           u16* __restrict__ xb, int N, int Mpad) {
    size_t i4 = (size_t)blockIdx.x * blockDim.x + threadIdx.x;
    size_t total4 = (size_t)2 * Mpad * 512 / 4;
    if (i4 >= total4) return;
    size_t base = i4 * 4;
    int prow = (int)(base >> 9);
    int br = prow >= Mpad;
    int lrow = prow - (br ? Mpad : 0);
    ushort4 o;
    if (lrow < N) {
        const float* src = br ? wtx : x;
        float4 v = *(const float4*)(src + (size_t)lrow * 512 + (base & 511));
        o = make_ushort4(f2b(v.x), f2b(v.y), f2b(v.z), f2b(v.w));
    } else {
        o = make_ushort4(0, 0, 0, 0);
    }
    *(ushort4*)(xb + base) = o;
}

__global__ void cast_wt_kernel(const float* __restrict__ W, u16* __restrict__ Wt) {
    int idx = blockIdx.x * blockDim.x + threadIdx.x;  // 512*512
    int n = idx >> 9, k = idx & 511;
    Wt[idx] = f2b(W[k * 512 + n]);
}

// ---------------- GEMM: h[M,512] = A[M,512] @ W[512,512], bf16 MFMA ----------------
// grid = (4 col tiles, M/128 row tiles): col index fastest -> A row-stripe L2 reuse.
__global__ __launch_bounds__(256, 2) void gemm_bf16(
    const u16* __restrict__ A, const u16* __restrict__ Bt, u16* __restrict__ C) {
    __shared__ u16 lA[128 * 32];
    __shared__ u16 lB[128 * 32];
    const int tid = threadIdx.x;
    const int w = tid >> 6, l = tid & 63;
    const int row0 = blockIdx.y * 128, col0 = blockIdx.x * 128;
    const int srow = (w << 4) + (l >> 2);
    const int scol = (l & 3) << 3;
    const int wr = w >> 1, wc = w & 1;
    const int mlane = l & 15, quad = l >> 4;

    f32x4 acc[4][4];
#pragma unroll
    for (int i = 0; i < 4; i++)
#pragma unroll
        for (int j = 0; j < 4; j++) acc[i][j] = f32x4{0.f, 0.f, 0.f, 0.f};

    for (int k0 = 0; k0 < 512; k0 += 32) {
#pragma unroll
        for (int s = 0; s < 2; ++s) {
            const u16* ga = A + (size_t)(row0 + s * 64 + srow) * 512 + (k0 + scol);
            const u16* gb = Bt + (size_t)(col0 + s * 64 + srow) * 512 + (k0 + scol);
            u16* la = lA + s * 2048 + w * 512;
            u16* lb = lB + s * 2048 + w * 512;
            __builtin_amdgcn_global_load_lds((const __attribute__((address_space(1))) void*)ga,
                                             (__attribute__((address_space(3))) void*)la, 16, 0, 0);
            __builtin_amdgcn_global_load_lds((const __attribute__((address_space(1))) void*)gb,
                                             (__attribute__((address_space(3))) void*)lb, 16, 0, 0);
        }
        __syncthreads();
        bf16x8 af[4], bfr[4];
#pragma unroll
        for (int i = 0; i < 4; i++) {
            af[i] = *(const bf16x8*)&lA[(wr * 64 + i * 16 + mlane) * 32 + quad * 8];
            bfr[i] = *(const bf16x8*)&lB[(wc * 64 + i * 16 + mlane) * 32 + quad * 8];
        }
#pragma unroll
        for (int i = 0; i < 4; i++)
#pragma unroll
            for (int j = 0; j < 4; j++)
                acc[i][j] = __builtin_amdgcn_mfma_f32_16x16x32_bf16(af[i], bfr[j], acc[i][j], 0, 0, 0);
        __syncthreads();
    }
#pragma unroll
    for (int i = 0; i < 4; i++)
#pragma unroll
        for (int j = 0; j < 4; j++)
#pragma unroll
            for (int r = 0; r < 4; r++) {
                int rg = row0 + wr * 64 + i * 16 + quad * 4 + r;
                int cg = col0 + wc * 64 + j * 16 + mlane;
                C[(size_t)rg * 512 + cg] = f2b(acc[i][j][r]);
            }
}

// ---------------- attention logits + fp8 cast of h, gid in [0,2N) ----------------
__global__ __launch_bounds__(256) void att_scores_cast(
    const u16* __restrict__ h, const float* __restrict__ att_src, const float* __restrict__ att_dst,
    float* __restrict__ asrc, float* __restrict__ adst, unsigned char* __restrict__ h8,
    int N, int Mpad) {
    int gid = blockIdx.x * 4 + (threadIdx.x >> 6);
    int lane = threadIdx.x & 63;
    if (gid >= 2 * N) return;
    int hrow = gid < N ? gid : gid - N + Mpad;
    int head = lane >> 4, sub = lane & 15;
    bf16x8 hv = *(const bf16x8*)(h + (size_t)hrow * 512 + lane * 8);
    float hf[8];
#pragma unroll
    for (int j = 0; j < 8; j++) hf[j] = b2f((u16)hv[j]);

    int lo = __builtin_amdgcn_cvt_pk_fp8_f32(hf[0], hf[1], 0, false);
    lo = __builtin_amdgcn_cvt_pk_fp8_f32(hf[2], hf[3], lo, true);
    int hi = __builtin_amdgcn_cvt_pk_fp8_f32(hf[4], hf[5], 0, false);
    hi = __builtin_amdgcn_cvt_pk_fp8_f32(hf[6], hf[7], hi, true);
    *(int2*)(h8 + (size_t)hrow * 512 + lane * 8) = make_int2(lo, hi);

    const float* as = att_src + head * 128 + sub * 8;
    const float* ad = att_dst + head * 128 + sub * 8;
    float ps = 0.f, pd = 0.f;
#pragma unroll
    for (int j = 0; j < 8; j++) {
        ps += hf[j] * as[j];
        pd += hf[j] * ad[j];
    }
#pragma unroll
    for (int o = 8; o >= 1; o >>= 1) {
        ps += __shfl_xor(ps, o, 16);
        pd += __shfl_xor(pd, o, 16);
    }
    if (sub == 0) {
        asrc[gid * 4 + head] = ps;
        adst[gid * 4 + head] = pd;
    }
}

// ---------------- CSR build over both graphs (2N nodes, 2E edges) ----------------
__global__ void csr_count(const int* __restrict__ adj, const int* __restrict__ wadj,
                          int E, int N, int* __restrict__ deg) {
    int i = blockIdx.x * blockDim.x + threadIdx.x;
    if (i < 2 * E) {
        int d = (i < E) ? adj[E + i] : (wadj[E + (i - E)] + N);
        atomicAdd(&deg[d], 1);
    }
}

// scanA: deg[i]+1 (self-loop folded here; deg starts at 0 via memset)
__global__ __launch_bounds__(256) void scanA(const int* __restrict__ deg, int* __restrict__ off,
                                             int* __restrict__ bsum, int n) {
    __shared__ int wsum[4];
    int tid = threadIdx.x, lane = tid & 63, wid = tid >> 6;
    int i = blockIdx.x * 256 + tid;
    int d = (i < n) ? deg[i] + 1 : 0;
    int x = d;
#pragma unroll
    for (int o = 1; o < 64; o <<= 1) {
        int y = __shfl_up(x, (unsigned)o, 64);
        if (lane >= o) x += y;
    }
    if (lane == 63) wsum[wid] = x;
    __syncthreads();
    int woff = 0;
    for (int j = 0; j < wid; ++j) woff += wsum[j];
    if (i < n) off[i] = woff + x - d;
    if (tid == 255) bsum[blockIdx.x] = woff + x;
}

__global__ __launch_bounds__(256) void scanB(const int* __restrict__ bsum, int* __restrict__ bbase,
                                             int nb, int* __restrict__ off, int n) {
    __shared__ int wsum[4];
    int tid = threadIdx.x, lane = tid & 63, wid = tid >> 6;
    int d = (tid < nb) ? bsum[tid] : 0;
    int x = d;
#pragma unroll
    for (int o = 1; o < 64; o <<= 1) {
        int y = __shfl_up(x, (unsigned)o, 64);
        if (lane >= o) x += y;
    }
    if (lane == 63) wsum[wid] = x;
    __syncthreads();
    int woff = 0;
    for (int j = 0; j < wid; ++j) woff += wsum[j];
    int excl = woff + x - d;
    if (tid < nb) bbase[tid] = excl;
    if (tid == nb - 1) off[n] = excl + d;
}

__global__ void scanC(int* __restrict__ off, const int* __restrict__ bbase,
                      int* __restrict__ cursor, int* __restrict__ csrc, int n) {
    int i = blockIdx.x * blockDim.x + threadIdx.x;
    if (i < n) {
        int o = off[i] + bbase[i >> 8];
        off[i] = o;
        csrc[o] = i;  // self loop (gid)
        cursor[i] = o + 1;
    }
}

__global__ void csr_scatter(const int* __restrict__ adj, const int* __restrict__ wadj,
                            int E, int N, int* __restrict__ cursor, int* __restrict__ csrc) {
    int i = blockIdx.x * blockDim.x + threadIdx.x;
    if (i < 2 * E) {
        int s, d;
        if (i < E) {
            s = adj[i];
            d = adj[E + i];
        } else {
            s = wadj[i - E] + N;
            d = wadj[E + (i - E)] + N;
        }
        int p = atomicAdd(&cursor[d], 1);
        csrc[p] = s;
    }
}

// ---------------- edge softmax, single pass (logits bounded -> no max needed) ----------------
// alpha[p*4+h] = exp(e); dinv[dst*4+h] = 1/sum.
__global__ __launch_bounds__(256) void compute_alpha_ns(
    const float* __restrict__ asrc, const float* __restrict__ adst,
    const int* __restrict__ off, const int* __restrict__ csrc,
    float* __restrict__ alpha, float* __restrict__ dinv, int N2) {
    int dst = blockIdx.x * 4 + (threadIdx.x >> 6);
    int lane = threadIdx.x & 63;
    if (dst >= N2) return;
    int p0 = off[dst], p1 = off[dst + 1];
    float4 ad = *(const float4*)(adst + (size_t)dst * 4);
    float s0 = 0.f, s1 = 0.f, s2 = 0.f, s3 = 0.f;
    for (int p = p0 + lane; p < p1; p += 64) {
        int s = csrc[p];
        float4 as = *(const float4*)(asrc + (size_t)s * 4);
        float e0 = as.x + ad.x; e0 = e0 >= 0.f ? e0 : 0.2f * e0;
        float e1 = as.y + ad.y; e1 = e1 >= 0.f ? e1 : 0.2f * e1;
        float e2 = as.z + ad.z; e2 = e2 >= 0.f ? e2 : 0.2f * e2;
        float e3 = as.w + ad.w; e3 = e3 >= 0.f ? e3 : 0.2f * e3;
        float x0 = __expf(e0), x1 = __expf(e1), x2 = __expf(e2), x3 = __expf(e3);
        *(float4*)(alpha + (size_t)p * 4) = make_float4(x0, x1, x2, x3);
        s0 += x0; s1 += x1; s2 += x2; s3 += x3;
    }
#pragma unroll
    for (int o = 32; o >= 1; o >>= 1) {
        s0 += __shfl_xor(s0, o); s1 += __shfl_xor(s1, o);
        s2 += __shfl_xor(s2, o); s3 += __shfl_xor(s3, o);
    }
    if (lane == 0) {
        *(float4*)(dinv + (size_t)dst * 4) =
            make_float4(1.f / (s0 + 1e-16f), 1.f / (s1 + 1e-16f),
                        1.f / (s2 + 1e-16f), 1.f / (s3 + 1e-16f));
    }
}

// ---------------- pure fp8 gather: 2 dsts/block, 4 ch/lane, dword loads ----------------
__global__ __launch_bounds__(256) void gat_aggregate4(
    const unsigned char* __restrict__ h8, const int* __restrict__ off,
    const int* __restrict__ csrc, const float* __restrict__ alpha,
    const float* __restrict__ dinv, const float* __restrict__ bias,
    float* __restrict__ partA, float* __restrict__ partB, int N, int Mpad) {
    int pair = threadIdx.x >> 7;       // 0 or 1: which dst of the block
    int pl = threadIdx.x & 127;        // pair-lane
    int c = pl << 2;                   // channel base (4 channels/lane)
    int head = pl >> 5;
    float4 bb = *(const float4*)(bias + c);
    float pA0 = 0.f, pA1 = 0.f, pA2 = 0.f, pA3 = 0.f;
    float pB0 = 0.f, pB1 = 0.f, pB2 = 0.f, pB3 = 0.f;
    const int N2 = 2 * N;
    const int hoff = Mpad - N;
    const int stride = gridDim.x * 2;
    for (int dst = blockIdx.x * 2 + pair; dst < N2; dst += stride) {
        int p0 = off[dst], p1 = off[dst + 1];
        float a0 = 0.f, a1 = 0.f, a2 = 0.f, a3 = 0.f;
        int p = p0;
        for (; p + 4 <= p1; p += 4) {
            int4 sv = *(const int4*)(csrc + p);
            float l0 = alpha[((p + 0) << 2) + head];
            float l1 = alpha[((p + 1) << 2) + head];
            float l2 = alpha[((p + 2) << 2) + head];
            float l3 = alpha[((p + 3) << 2) + head];
            int r0 = sv.x < N ? sv.x : sv.x + hoff;
            int r1 = sv.y < N ? sv.y : sv.y + hoff;
            int r2 = sv.z < N ? sv.z : sv.z + hoff;
            int r3 = sv.w < N ? sv.w : sv.w + hoff;
            unsigned v0 = *(const unsigned*)(h8 + ((r0 << 9) + c));
            unsigned v1 = *(const unsigned*)(h8 + ((r1 << 9) + c));
            unsigned v2 = *(const unsigned*)(h8 + ((r2 << 9) + c));
            unsigned v3 = *(const unsigned*)(h8 + ((r3 << 9) + c));
            a0 += l0 * __builtin_amdgcn_cvt_f32_fp8(v0, 0);
            a1 += l0 * __builtin_amdgcn_cvt_f32_fp8(v0, 1);
            a2 += l0 * __builtin_amdgcn_cvt_f32_fp8(v0, 2);
            a3 += l0 * __builtin_amdgcn_cvt_f32_fp8(v0, 3);
            a0 += l1 * __builtin_amdgcn_cvt_f32_fp8(v1, 0);
            a1 += l1 * __builtin_amdgcn_cvt_f32_fp8(v1, 1);
            a2 += l1 * __builtin_amdgcn_cvt_f32_fp8(v1, 2);
            a3 += l1 * __builtin_amdgcn_cvt_f32_fp8(v1, 3);
            a0 += l2 * __builtin_amdgcn_cvt_f32_fp8(v2, 0);
            a1 += l2 * __builtin_amdgcn_cvt_f32_fp8(v2, 1);
            a2 += l2 * __builtin_amdgcn_cvt_f32_fp8(v2, 2);
            a3 += l2 * __builtin_amdgcn_cvt_f32_fp8(v2, 3);
            a0 += l3 * __builtin_amdgcn_cvt_f32_fp8(v3, 0);
            a1 += l3 * __builtin_amdgcn_cvt_f32_fp8(v3, 1);
            a2 += l3 * __builtin_amdgcn_cvt_f32_fp8(v3, 2);
            a3 += l3 * __builtin_amdgcn_cvt_f32_fp8(v3, 3);
        }
        for (; p < p1; ++p) {
            int s = csrc[p];
            float l0 = alpha[(p << 2) + head];
            int r = s < N ? s : s + hoff;
            unsigned v = *(const unsigned*)(h8 + ((r << 9) + c));
            a0 += l0 * __builtin_amdgcn_cvt_f32_fp8(v, 0);
            a1 += l0 * __builtin_amdgcn_cvt_f32_fp8(v, 1);
            a2 += l0 * __builtin_amdgcn_cvt_f32_fp8(v, 2);
            a3 += l0 * __builtin_amdgcn_cvt_f32_fp8(v, 3);
        }
        float inv = dinv[(dst << 2) + head];
        float o0 = a0 * inv + bb.x;
        float o1 = a1 * inv + bb.y;
        float o2 = a2 * inv + bb.z;
        float o3 = a3 * inv + bb.w;
        o0 = o0 >= 0.f ? o0 : 0.01f * o0;
        o1 = o1 >= 0.f ? o1 : 0.01f * o1;
        o2 = o2 >= 0.f ? o2 : 0.01f * o2;
        o3 = o3 >= 0.f ? o3 : 0.01f * o3;
        if (dst < N) {
            pA0 += o0; pA1 += o1; pA2 += o2; pA3 += o3;
        } else {
            pB0 += o0; pB1 += o1; pB2 += o2; pB3 += o3;
        }
    }
    int prow = ((blockIdx.x & 63) << 9) + c;
    atomicAdd(&partA[prow + 0], pA0);
    atomicAdd(&partA[prow + 1], pA1);
    atomicAdd(&partA[prow + 2], pA2);
    atomicAdd(&partA[prow + 3], pA3);
    atomicAdd(&partB[prow + 0], pB0);
    atomicAdd(&partB[prow + 1], pB1);
    atomicAdd(&partB[prow + 2], pB2);
    atomicAdd(&partB[prow + 3], pB3);
}

// ---------------- reductions + fc ----------------
__global__ void reduce_partials(const float* __restrict__ pA, const float* __restrict__ pB,
                                float* __restrict__ g, float invN) {
    int idx = blockIdx.x * blockDim.x + threadIdx.x;  // 0..1023
    const float* p = (idx < 512) ? pA : pB;
    int c = idx & 511;
    float s = 0.f;
    for (int r = 0; r < 64; ++r) s += p[r * 512 + c];
    g[idx] = s * invN;
}

__global__ __launch_bounds__(256) void fc_final(
    const float* __restrict__ g, const float* __restrict__ w, const float* __restrict__ b,
    float* __restrict__ out) {
    __shared__ float rA[256], rB[256];
    int t = threadIdx.x;
    int jj = t & 31, ks = t >> 5;
    int j = blockIdx.x * 32 + jj;
    float sA = 0.f, sB = 0.f;
    for (int k = ks * 64; k < ks * 64 + 64; ++k) {
        float wv = w[k * 512 + j];
        sA += g[k] * wv;
        sB += g[512 + k] * wv;
    }
    rA[t] = sA;
    rB[t] = sB;
    __syncthreads();
    if (ks == 0) {
#pragma unroll
        for (int s2 = 1; s2 < 8; ++s2) {
            sA += rA[jj + 32 * s2];
            sB += rB[jj + 32 * s2];
        }
        sA += b[j];
        sB += b[j];
        sA = sA >= 0.f ? sA : 0.01f * sA;
        sB = sB >= 0.f ? sB : 0.01f * sB;
        out[j] = sA;
        out[512 + j] = sB;
        out[1024 + j] = sA - sB;
    }
}

// ---------------- launch ----------------
extern "C" void kernel_launch(void* const* d_in, const int* in_sizes, int n_in,
                              void* d_out, int out_size, void* d_ws, size_t ws_size,
                              hipStream_t stream) {
    const float* x = (const float*)d_in[0];
    const int* adj = (const int*)d_in[1];
    const float* wtx = (const float*)d_in[2];
    const int* wadj = (const int*)d_in[3];
    const float* W = (const float*)d_in[4];
    const float* att_s = (const float*)d_in[5];
    const float* att_d = (const float*)d_in[6];
    const float* bias = (const float*)d_in[7];
    const float* fc1w = (const float*)d_in[8];
    const float* fc1b = (const float*)d_in[9];
    float* out = (float*)d_out;

    const int N = in_sizes[0] / 512;  // 20000
    const int E = in_sizes[1] / 2;    // 320000
    const int Mpad = ((N + 127) / 128) * 128;
    const int N2 = 2 * N;
    const int nb = (N2 + 255) / 256;

    char* p = (char*)d_ws;
    auto alloc = [&](size_t bytes) -> char* {
        char* r = p;
        p += (bytes + 255) & ~(size_t)255;
        return r;
    };
    u16* xb = (u16*)alloc((size_t)2 * Mpad * 512 * 2);
    u16* hb = (u16*)alloc((size_t)2 * Mpad * 512 * 2);
    unsigned char* h8 = (unsigned char*)alloc((size_t)2 * Mpad * 512);
    u16* Wt = (u16*)alloc(512 * 512 * 2);
    float* asrc = (float*)alloc((size_t)N2 * 4 * 4);
    float* adst = (float*)alloc((size_t)N2 * 4 * 4);
    int* deg = (int*)alloc((size_t)N2 * 4);
    int* off = (int*)alloc((size_t)(N2 + 1) * 4);
    int* cursor = (int*)alloc((size_t)N2 * 4);
    int* bsum = (int*)alloc(256 * 4);
    int* bbase = (int*)alloc(256 * 4);
    int* csrc = (int*)alloc((size_t)2 * (E + N) * 4);
    float* alpha = (float*)alloc((size_t)2 * (E + N) * 4 * 4);
    float* dinv = (float*)alloc((size_t)N2 * 4 * 4);
    float* partA = (float*)alloc(64 * 512 * 4);
    float* partB = (float*)alloc(64 * 512 * 4);
    float* gvec = (float*)alloc(1024 * 4);

    hipMemsetAsync(partA, 0, 64 * 512 * 4, stream);
    hipMemsetAsync(partB, 0, 64 * 512 * 4, stream);
    hipMemsetAsync(deg, 0, (size_t)N2 * 4, stream);
    cast_wt_kernel<<<(512 * 512) / 256, 256, 0, stream>>>(W, Wt);

    size_t total4 = (size_t)2 * Mpad * 512 / 4;
    cast_x_all<<<(int)((total4 + 255) / 256), 256, 0, stream>>>(x, wtx, xb, N, Mpad);

    // CSR build (independent of GEMM)
    csr_count<<<(2 * E + 255) / 256, 256, 0, stream>>>(adj, wadj, E, N, deg);
    scanA<<<nb, 256, 0, stream>>>(deg, off, bsum, N2);
    scanB<<<1, 256, 0, stream>>>(bsum, bbase, nb, off, N2);
    scanC<<<nb, 256, 0, stream>>>(off, bbase, cursor, csrc, N2);
    csr_scatter<<<(2 * E + 255) / 256, 256, 0, stream>>>(adj, wadj, E, N, cursor, csrc);

    // GEMM over both branches (col tiles fastest for A L2 reuse)
    dim3 gg(4, 2 * Mpad / 128, 1);
    gemm_bf16<<<gg, 256, 0, stream>>>(xb, Wt, hb);
    att_scores_cast<<<(N2 + 3) / 4, 256, 0, stream>>>(hb, att_s, att_d, asrc, adst, h8, N, Mpad);

    compute_alpha_ns<<<(N2 + 3) / 4, 256, 0, stream>>>(asrc, adst, off, csrc, alpha, dinv, N2);
    gat_aggregate4<<<2048, 256, 0, stream>>>(h8, off, csrc, alpha, dinv, bias, partA, partB,
                                             N, Mpad);

    reduce_partials<<<4, 256, 0, stream>>>(partA, partB, gvec, 1.0f / (float)N);
    fc_final<<<16, 256, 0, stream>>>(gvec, fc1w, fc1b, out);
}

// Round 6
// 359.879 us; speedup vs baseline: 1.1266x; 1.1266x over previous
//
#include <hip/hip_runtime.h>
#include <hip/hip_bf16.h>

typedef unsigned short u16;
typedef short bf16x8 __attribute__((ext_vector_type(8)));
typedef float f32x4 __attribute__((ext_vector_type(4)));
typedef float f32x2 __attribute__((ext_vector_type(2)));

__device__ __forceinline__ u16 f2b(float f) {
    unsigned x = __float_as_uint(f);
    return (u16)((x + 0x7fffu + ((x >> 16) & 1u)) >> 16);
}

// ---------------- cast: both branches in one launch ----------------
__global__ void cast_x_all(const float* __restrict__ x, const float* __restrict__ wtx,
                           u16* __restrict__ xb, int N, int Mpad) {
    size_t i4 = (size_t)blockIdx.x * blockDim.x + threadIdx.x;
    size_t total4 = (size_t)2 * Mpad * 512 / 4;
    if (i4 >= total4) return;
    size_t base = i4 * 4;
    int prow = (int)(base >> 9);
    int br = prow >= Mpad;
    int lrow = prow - (br ? Mpad : 0);
    ushort4 o;
    if (lrow < N) {
        const float* src = br ? wtx : x;
        float4 v = *(const float4*)(src + (size_t)lrow * 512 + (base & 511));
        o = make_ushort4(f2b(v.x), f2b(v.y), f2b(v.z), f2b(v.w));
    } else {
        o = make_ushort4(0, 0, 0, 0);
    }
    *(ushort4*)(xb + base) = o;
}

__global__ void cast_wt_kernel(const float* __restrict__ W, u16* __restrict__ Wt) {
    int idx = blockIdx.x * blockDim.x + threadIdx.x;  // 512*512
    int n = idx >> 9, k = idx & 511;
    Wt[idx] = f2b(W[k * 512 + n]);
}

// ---------------- GEMM fused: h8 (fp8) + per-node attention logits ----------------
// grid (2*Mpad/128 row tiles [fastest], 4 col tiles == heads).
// Writes: h8[row,512] fp8; asrc/adst[gid*4+head] from f32 accumulators.
__global__ __launch_bounds__(256, 2) void gemm_fused(
    const u16* __restrict__ A, const u16* __restrict__ Bt, unsigned char* __restrict__ h8,
    const float* __restrict__ att_src, const float* __restrict__ att_dst,
    float* __restrict__ asrc, float* __restrict__ adst, int N, int Mpad) {
    __shared__ u16 lA[128 * 32];
    __shared__ u16 lB[128 * 32];
    __shared__ float sred[2][128][2];
    const int tid = threadIdx.x;
    const int w = tid >> 6, l = tid & 63;
    const int row0 = blockIdx.x * 128;
    const int head = blockIdx.y;
    const int col0 = head * 128;
    const int srow = (w << 4) + (l >> 2);
    const int scol = (l & 3) << 3;
    const int wr = w >> 1, wc = w & 1;
    const int mlane = l & 15, quad = l >> 4;

    f32x4 acc[4][4];
#pragma unroll
    for (int i = 0; i < 4; i++)
#pragma unroll
        for (int j = 0; j < 4; j++) acc[i][j] = f32x4{0.f, 0.f, 0.f, 0.f};

    for (int k0 = 0; k0 < 512; k0 += 32) {
#pragma unroll
        for (int s = 0; s < 2; ++s) {
            const u16* ga = A + (size_t)(row0 + s * 64 + srow) * 512 + (k0 + scol);
            const u16* gb = Bt + (size_t)(col0 + s * 64 + srow) * 512 + (k0 + scol);
            u16* la = lA + s * 2048 + w * 512;
            u16* lb = lB + s * 2048 + w * 512;
            __builtin_amdgcn_global_load_lds((const __attribute__((address_space(1))) void*)ga,
                                             (__attribute__((address_space(3))) void*)la, 16, 0, 0);
            __builtin_amdgcn_global_load_lds((const __attribute__((address_space(1))) void*)gb,
                                             (__attribute__((address_space(3))) void*)lb, 16, 0, 0);
        }
        __syncthreads();
        bf16x8 af[4], bfr[4];
#pragma unroll
        for (int i = 0; i < 4; i++) {
            af[i] = *(const bf16x8*)&lA[(wr * 64 + i * 16 + mlane) * 32 + quad * 8];
            bfr[i] = *(const bf16x8*)&lB[(wc * 64 + i * 16 + mlane) * 32 + quad * 8];
        }
#pragma unroll
        for (int i = 0; i < 4; i++)
#pragma unroll
            for (int j = 0; j < 4; j++)
                acc[i][j] = __builtin_amdgcn_mfma_f32_16x16x32_bf16(af[i], bfr[j], acc[i][j], 0, 0, 0);
        __syncthreads();
    }

    // attention weights for this head, this lane's 4 col positions
    float as_j[4], ad_j[4];
#pragma unroll
    for (int j = 0; j < 4; j++) {
        as_j[j] = att_src[col0 + wc * 64 + j * 16 + mlane];
        ad_j[j] = att_dst[col0 + wc * 64 + j * 16 + mlane];
    }
#pragma unroll
    for (int i = 0; i < 4; i++) {
#pragma unroll
        for (int r = 0; r < 4; r++) {
            float vs = 0.f, vd = 0.f;
#pragma unroll
            for (int j = 0; j < 4; j++) {
                float hv = acc[i][j][r];
                vs += hv * as_j[j];
                vd += hv * ad_j[j];
            }
#pragma unroll
            for (int o = 8; o >= 1; o >>= 1) {
                vs += __shfl_xor(vs, o);
                vd += __shfl_xor(vd, o);
            }
            if (mlane == 0) {
                int lrow = wr * 64 + i * 16 + quad * 4 + r;
                sred[0][lrow][wc] = vs;
                sred[1][lrow][wc] = vd;
            }
        }
    }
    // fp8 h stores (same mapping as old bf16 C store)
#pragma unroll
    for (int i = 0; i < 4; i++)
#pragma unroll
        for (int j = 0; j < 4; j++)
#pragma unroll
            for (int r = 0; r < 4; r++) {
                int rg = row0 + wr * 64 + i * 16 + quad * 4 + r;
                int cg = col0 + wc * 64 + j * 16 + mlane;
                float v = acc[i][j][r];
                unsigned pk = __builtin_amdgcn_cvt_pk_fp8_f32(v, v, 0, false);
                h8[(size_t)rg * 512 + cg] = (unsigned char)(pk & 0xff);
            }
    __syncthreads();
    {
        int row = tid & 127, which = tid >> 7;
        int rg = row0 + row;
        int gid = rg < N ? rg : ((rg >= Mpad && rg < Mpad + N) ? rg - Mpad + N : -1);
        if (gid >= 0) {
            float v = sred[which][row][0] + sred[which][row][1];
            (which ? adst : asrc)[(gid << 2) + head] = v;
        }
    }
}

// ---------------- CSR build over both graphs (2N nodes, 2E edges) ----------------
__global__ void csr_count(const int* __restrict__ adj, const int* __restrict__ wadj,
                          int E, int N, int* __restrict__ deg) {
    int i = blockIdx.x * blockDim.x + threadIdx.x;
    if (i < 2 * E) {
        int d = (i < E) ? adj[E + i] : (wadj[E + (i - E)] + N);
        atomicAdd(&deg[d], 1);
    }
}

// scanA: deg[i]+1 (self-loop folded; deg zeroed by memset)
__global__ __launch_bounds__(256) void scanA(const int* __restrict__ deg, int* __restrict__ off,
                                             int* __restrict__ bsum, int n) {
    __shared__ int wsum[4];
    int tid = threadIdx.x, lane = tid & 63, wid = tid >> 6;
    int i = blockIdx.x * 256 + tid;
    int d = (i < n) ? deg[i] + 1 : 0;
    int x = d;
#pragma unroll
    for (int o = 1; o < 64; o <<= 1) {
        int y = __shfl_up(x, (unsigned)o, 64);
        if (lane >= o) x += y;
    }
    if (lane == 63) wsum[wid] = x;
    __syncthreads();
    int woff = 0;
    for (int j = 0; j < wid; ++j) woff += wsum[j];
    if (i < n) off[i] = woff + x - d;
    if (tid == 255) bsum[blockIdx.x] = woff + x;
}

__global__ __launch_bounds__(256) void scanB(const int* __restrict__ bsum, int* __restrict__ bbase,
                                             int nb, int* __restrict__ off, int n) {
    __shared__ int wsum[4];
    int tid = threadIdx.x, lane = tid & 63, wid = tid >> 6;
    int d = (tid < nb) ? bsum[tid] : 0;
    int x = d;
#pragma unroll
    for (int o = 1; o < 64; o <<= 1) {
        int y = __shfl_up(x, (unsigned)o, 64);
        if (lane >= o) x += y;
    }
    if (lane == 63) wsum[wid] = x;
    __syncthreads();
    int woff = 0;
    for (int j = 0; j < wid; ++j) woff += wsum[j];
    int excl = woff + x - d;
    if (tid < nb) bbase[tid] = excl;
    if (tid == nb - 1) off[n] = excl + d;
}

__global__ void scanC(int* __restrict__ off, const int* __restrict__ bbase,
                      int* __restrict__ cursor, int* __restrict__ csrc, int n) {
    int i = blockIdx.x * blockDim.x + threadIdx.x;
    if (i < n) {
        int o = off[i] + bbase[i >> 8];
        off[i] = o;
        csrc[o] = i;  // self loop (gid)
        cursor[i] = o + 1;
    }
}

__global__ void csr_scatter(const int* __restrict__ adj, const int* __restrict__ wadj,
                            int E, int N, int* __restrict__ cursor, int* __restrict__ csrc) {
    int i = blockIdx.x * blockDim.x + threadIdx.x;
    if (i < 2 * E) {
        int s, d;
        if (i < E) {
            s = adj[i];
            d = adj[E + i];
        } else {
            s = wadj[i - E] + N;
            d = wadj[E + (i - E)] + N;
        }
        int p = atomicAdd(&cursor[d], 1);
        csrc[p] = s;
    }
}

// ---------------- fused softmax + gather, wave-per-dst, 8 ch/lane ----------------
__device__ __forceinline__ void edge_acc(int s, float ad, int head, int N, int hoff,
                                         const float* __restrict__ asrc,
                                         const unsigned char* __restrict__ h8, int c,
                                         float* acc, float& dsum) {
    float e = asrc[(s << 2) + head] + ad;
    e = fmaxf(e, 0.2f * e);  // leaky relu
    float ex = __expf(e);
    dsum += ex;
    int r = s < N ? s : s + hoff;
    int2 hv = *(const int2*)(h8 + (((size_t)r) << 9) + c);
    f32x2 f01 = __builtin_amdgcn_cvt_pk_f32_fp8(hv.x, false);
    f32x2 f23 = __builtin_amdgcn_cvt_pk_f32_fp8(hv.x, true);
    f32x2 f45 = __builtin_amdgcn_cvt_pk_f32_fp8(hv.y, false);
    f32x2 f67 = __builtin_amdgcn_cvt_pk_f32_fp8(hv.y, true);
    acc[0] += ex * f01.x; acc[1] += ex * f01.y;
    acc[2] += ex * f23.x; acc[3] += ex * f23.y;
    acc[4] += ex * f45.x; acc[5] += ex * f45.y;
    acc[6] += ex * f67.x; acc[7] += ex * f67.y;
}

__global__ __launch_bounds__(256) void gat_aggregate5(
    const unsigned char* __restrict__ h8, const float* __restrict__ asrc,
    const float* __restrict__ adst, const int* __restrict__ off, const int* __restrict__ csrc,
    const float* __restrict__ bias, float* __restrict__ partAB, int N, int Mpad) {
    __shared__ float spool[1024];
    int tid = threadIdx.x;
    for (int i = tid; i < 1024; i += 256) spool[i] = 0.f;
    __syncthreads();
    int wv = tid >> 6, l = tid & 63;
    int c = l << 3;        // 8 channels per lane
    int head = l >> 4;
    float bb[8];
#pragma unroll
    for (int k = 0; k < 8; ++k) bb[k] = bias[c + k];
    float poolA[8] = {0.f, 0.f, 0.f, 0.f, 0.f, 0.f, 0.f, 0.f};
    float poolB[8] = {0.f, 0.f, 0.f, 0.f, 0.f, 0.f, 0.f, 0.f};
    const int N2 = 2 * N, hoff = Mpad - N;
    const int stride = gridDim.x << 2;
    for (int dst = (blockIdx.x << 2) + wv; dst < N2; dst += stride) {
        int p0 = off[dst], p1 = off[dst + 1];
        float ad = adst[(dst << 2) + head];
        float acc[8] = {0.f, 0.f, 0.f, 0.f, 0.f, 0.f, 0.f, 0.f};
        float dsum = 0.f;
        int p = p0;
        for (; p + 4 <= p1; p += 4) {
            int4 sv = *(const int4*)(csrc + p);
            edge_acc(sv.x, ad, head, N, hoff, asrc, h8, c, acc, dsum);
            edge_acc(sv.y, ad, head, N, hoff, asrc, h8, c, acc, dsum);
            edge_acc(sv.z, ad, head, N, hoff, asrc, h8, c, acc, dsum);
            edge_acc(sv.w, ad, head, N, hoff, asrc, h8, c, acc, dsum);
        }
        for (; p < p1; ++p)
            edge_acc(csrc[p], ad, head, N, hoff, asrc, h8, c, acc, dsum);
        float inv = 1.f / (dsum + 1e-16f);
        if (dst < N) {
#pragma unroll
            for (int k = 0; k < 8; ++k) {
                float o = acc[k] * inv + bb[k];
                poolA[k] += fmaxf(o, 0.01f * o);
            }
        } else {
#pragma unroll
            for (int k = 0; k < 8; ++k) {
                float o = acc[k] * inv + bb[k];
                poolB[k] += fmaxf(o, 0.01f * o);
            }
        }
    }
#pragma unroll
    for (int k = 0; k < 8; ++k) {
        atomicAdd(&spool[c + k], poolA[k]);
        atomicAdd(&spool[512 + c + k], poolB[k]);
    }
    __syncthreads();
    int base = (blockIdx.x & 63) << 9;
    for (int i = tid; i < 1024; i += 256) {
        float* dp = (i < 512) ? (partAB + base + i) : (partAB + 64 * 512 + base + (i - 512));
        atomicAdd(dp, spool[i]);
    }
}

// ---------------- fused mean-pool reduce + fc + concat ----------------
__global__ __launch_bounds__(256) void fc_final2(
    const float* __restrict__ partAB, const float* __restrict__ w, const float* __restrict__ b,
    float* __restrict__ out, float invN) {
    __shared__ float gA[512], gB[512];
    __shared__ float rA[256], rB[256];
    int t = threadIdx.x;
    for (int i = t; i < 512; i += 256) {
        float sA = 0.f, sB = 0.f;
        for (int r = 0; r < 64; ++r) {
            sA += partAB[r * 512 + i];
            sB += partAB[64 * 512 + r * 512 + i];
        }
        gA[i] = sA * invN;
        gB[i] = sB * invN;
    }
    __syncthreads();
    int jj = t & 31, ks = t >> 5;
    int j = blockIdx.x * 32 + jj;
    float sA = 0.f, sB = 0.f;
    for (int k = ks * 64; k < ks * 64 + 64; ++k) {
        float wv = w[k * 512 + j];
        sA += gA[k] * wv;
        sB += gB[k] * wv;
    }
    rA[t] = sA;
    rB[t] = sB;
    __syncthreads();
    if (ks == 0) {
#pragma unroll
        for (int s2 = 1; s2 < 8; ++s2) {
            sA += rA[jj + 32 * s2];
            sB += rB[jj + 32 * s2];
        }
        sA += b[j];
        sB += b[j];
        sA = sA >= 0.f ? sA : 0.01f * sA;
        sB = sB >= 0.f ? sB : 0.01f * sB;
        out[j] = sA;
        out[512 + j] = sB;
        out[1024 + j] = sA - sB;
    }
}

// ---------------- launch ----------------
extern "C" void kernel_launch(void* const* d_in, const int* in_sizes, int n_in,
                              void* d_out, int out_size, void* d_ws, size_t ws_size,
                              hipStream_t stream) {
    const float* x = (const float*)d_in[0];
    const int* adj = (const int*)d_in[1];
    const float* wtx = (const float*)d_in[2];
    const int* wadj = (const int*)d_in[3];
    const float* W = (const float*)d_in[4];
    const float* att_s = (const float*)d_in[5];
    const float* att_d = (const float*)d_in[6];
    const float* bias = (const float*)d_in[7];
    const float* fc1w = (const float*)d_in[8];
    const float* fc1b = (const float*)d_in[9];
    float* out = (float*)d_out;

    const int N = in_sizes[0] / 512;  // 20000
    const int E = in_sizes[1] / 2;    // 320000
    const int Mpad = ((N + 127) / 128) * 128;
    const int N2 = 2 * N;
    const int nb = (N2 + 255) / 256;

    char* p = (char*)d_ws;
    auto alloc = [&](size_t bytes) -> char* {
        char* r = p;
        p += (bytes + 255) & ~(size_t)255;
        return r;
    };
    u16* xb = (u16*)alloc((size_t)2 * Mpad * 512 * 2);
    unsigned char* h8 = (unsigned char*)alloc((size_t)2 * Mpad * 512);
    u16* Wt = (u16*)alloc(512 * 512 * 2);
    float* asrc = (float*)alloc((size_t)N2 * 4 * 4);
    float* adst = (float*)alloc((size_t)N2 * 4 * 4);
    int* deg = (int*)alloc((size_t)N2 * 4);
    int* off = (int*)alloc((size_t)(N2 + 1) * 4);
    int* cursor = (int*)alloc((size_t)N2 * 4);
    int* bsum = (int*)alloc(256 * 4);
    int* bbase = (int*)alloc(256 * 4);
    int* csrc = (int*)alloc((size_t)2 * (E + N) * 4);
    float* partAB = (float*)alloc((size_t)2 * 64 * 512 * 4);

    hipMemsetAsync(partAB, 0, (size_t)2 * 64 * 512 * 4, stream);
    hipMemsetAsync(deg, 0, (size_t)N2 * 4, stream);
    cast_wt_kernel<<<(512 * 512) / 256, 256, 0, stream>>>(W, Wt);

    size_t total4 = (size_t)2 * Mpad * 512 / 4;
    cast_x_all<<<(int)((total4 + 255) / 256), 256, 0, stream>>>(x, wtx, xb, N, Mpad);

    // CSR build (independent of GEMM)
    csr_count<<<(2 * E + 255) / 256, 256, 0, stream>>>(adj, wadj, E, N, deg);
    scanA<<<nb, 256, 0, stream>>>(deg, off, bsum, N2);
    scanB<<<1, 256, 0, stream>>>(bsum, bbase, nb, off, N2);
    scanC<<<nb, 256, 0, stream>>>(off, bbase, cursor, csrc, N2);
    csr_scatter<<<(2 * E + 255) / 256, 256, 0, stream>>>(adj, wadj, E, N, cursor, csrc);

    // fused GEMM: writes h8 + attention logits (row tiles fastest)
    dim3 gg(2 * Mpad / 128, 4, 1);
    gemm_fused<<<gg, 256, 0, stream>>>(xb, Wt, h8, att_s, att_d, asrc, adst, N, Mpad);

    gat_aggregate5<<<2048, 256, 0, stream>>>(h8, asrc, adst, off, csrc, bias, partAB, N, Mpad);

    fc_final2<<<16, 256, 0, stream>>>(partAB, fc1w, fc1b, out, 1.0f / (float)N);
}

// Round 7
// 354.481 us; speedup vs baseline: 1.1438x; 1.0152x over previous
//
#include <hip/hip_runtime.h>
#include <hip/hip_bf16.h>

typedef unsigned short u16;
typedef short bf16x8 __attribute__((ext_vector_type(8)));
typedef float f32x4 __attribute__((ext_vector_type(4)));
typedef float f32x2 __attribute__((ext_vector_type(2)));

#define CH_SHIFT 12  // 4096 h8 rows = 2 MiB fp8 window per src-chunk

__device__ __forceinline__ u16 f2b(float f) {
    unsigned x = __float_as_uint(f);
    return (u16)((x + 0x7fffu + ((x >> 16) & 1u)) >> 16);
}

// ---------------- cast: both branches in one launch ----------------
__global__ void cast_x_all(const float* __restrict__ x, const float* __restrict__ wtx,
                           u16* __restrict__ xb, int N, int Mpad) {
    size_t i4 = (size_t)blockIdx.x * blockDim.x + threadIdx.x;
    size_t total4 = (size_t)2 * Mpad * 512 / 4;
    if (i4 >= total4) return;
    size_t base = i4 * 4;
    int prow = (int)(base >> 9);
    int br = prow >= Mpad;
    int lrow = prow - (br ? Mpad : 0);
    ushort4 o;
    if (lrow < N) {
        const float* src = br ? wtx : x;
        float4 v = *(const float4*)(src + (size_t)lrow * 512 + (base & 511));
        o = make_ushort4(f2b(v.x), f2b(v.y), f2b(v.z), f2b(v.w));
    } else {
        o = make_ushort4(0, 0, 0, 0);
    }
    *(ushort4*)(xb + base) = o;
}

__global__ void cast_wt_kernel(const float* __restrict__ W, u16* __restrict__ Wt) {
    int idx = blockIdx.x * blockDim.x + threadIdx.x;  // 512*512
    int n = idx >> 9, k = idx & 511;
    Wt[idx] = f2b(W[k * 512 + n]);
}

// ---------------- GEMM fused: h8 (fp8) + per-node attention logits ----------------
// grid (4 heads [fastest -> A-stripe L2/L3 reuse], 2*Mpad/128 row tiles).
__global__ __launch_bounds__(256, 2) void gemm_fused(
    const u16* __restrict__ A, const u16* __restrict__ Bt, unsigned char* __restrict__ h8,
    const float* __restrict__ att_src, const float* __restrict__ att_dst,
    float* __restrict__ asrc, float* __restrict__ adst, int N, int Mpad) {
    __shared__ u16 lA[128 * 32];
    __shared__ u16 lB[128 * 32];
    __shared__ float sred[2][128][2];
    const int tid = threadIdx.x;
    const int w = tid >> 6, l = tid & 63;
    const int row0 = blockIdx.y * 128;
    const int head = blockIdx.x;
    const int col0 = head * 128;
    const int srow = (w << 4) + (l >> 2);
    const int scol = (l & 3) << 3;
    const int wr = w >> 1, wc = w & 1;
    const int mlane = l & 15, quad = l >> 4;

    f32x4 acc[4][4];
#pragma unroll
    for (int i = 0; i < 4; i++)
#pragma unroll
        for (int j = 0; j < 4; j++) acc[i][j] = f32x4{0.f, 0.f, 0.f, 0.f};

    for (int k0 = 0; k0 < 512; k0 += 32) {
#pragma unroll
        for (int s = 0; s < 2; ++s) {
            const u16* ga = A + (size_t)(row0 + s * 64 + srow) * 512 + (k0 + scol);
            const u16* gb = Bt + (size_t)(col0 + s * 64 + srow) * 512 + (k0 + scol);
            u16* la = lA + s * 2048 + w * 512;
            u16* lb = lB + s * 2048 + w * 512;
            __builtin_amdgcn_global_load_lds((const __attribute__((address_space(1))) void*)ga,
                                             (__attribute__((address_space(3))) void*)la, 16, 0, 0);
            __builtin_amdgcn_global_load_lds((const __attribute__((address_space(1))) void*)gb,
                                             (__attribute__((address_space(3))) void*)lb, 16, 0, 0);
        }
        __syncthreads();
        bf16x8 af[4], bfr[4];
#pragma unroll
        for (int i = 0; i < 4; i++) {
            af[i] = *(const bf16x8*)&lA[(wr * 64 + i * 16 + mlane) * 32 + quad * 8];
            bfr[i] = *(const bf16x8*)&lB[(wc * 64 + i * 16 + mlane) * 32 + quad * 8];
        }
#pragma unroll
        for (int i = 0; i < 4; i++)
#pragma unroll
            for (int j = 0; j < 4; j++)
                acc[i][j] = __builtin_amdgcn_mfma_f32_16x16x32_bf16(af[i], bfr[j], acc[i][j], 0, 0, 0);
        __syncthreads();
    }

    float as_j[4], ad_j[4];
#pragma unroll
    for (int j = 0; j < 4; j++) {
        as_j[j] = att_src[col0 + wc * 64 + j * 16 + mlane];
        ad_j[j] = att_dst[col0 + wc * 64 + j * 16 + mlane];
    }
#pragma unroll
    for (int i = 0; i < 4; i++) {
#pragma unroll
        for (int r = 0; r < 4; r++) {
            float vs = 0.f, vd = 0.f;
#pragma unroll
            for (int j = 0; j < 4; j++) {
                float hv = acc[i][j][r];
                vs += hv * as_j[j];
                vd += hv * ad_j[j];
            }
#pragma unroll
            for (int o = 8; o >= 1; o >>= 1) {
                vs += __shfl_xor(vs, o);
                vd += __shfl_xor(vd, o);
            }
            if (mlane == 0) {
                int lrow = wr * 64 + i * 16 + quad * 4 + r;
                sred[0][lrow][wc] = vs;
                sred[1][lrow][wc] = vd;
            }
        }
    }
#pragma unroll
    for (int i = 0; i < 4; i++)
#pragma unroll
        for (int j = 0; j < 4; j++)
#pragma unroll
            for (int r = 0; r < 4; r++) {
                int rg = row0 + wr * 64 + i * 16 + quad * 4 + r;
                int cg = col0 + wc * 64 + j * 16 + mlane;
                float v = acc[i][j][r];
                unsigned pk = __builtin_amdgcn_cvt_pk_fp8_f32(v, v, 0, false);
                h8[(size_t)rg * 512 + cg] = (unsigned char)(pk & 0xff);
            }
    __syncthreads();
    {
        int row = tid & 127, which = tid >> 7;
        int rg = row0 + row;
        int gid = rg < N ? rg : ((rg >= Mpad && rg < Mpad + N) ? rg - Mpad + N : -1);
        if (gid >= 0) {
            float v = sred[which][row][0] + sred[which][row][1];
            (which ? adst : asrc)[(gid << 2) + head] = v;
        }
    }
}

// ---------------- 2-level CSR: segments (dst, src-chunk) ----------------
// seg = dst*NC + (hrow(src) >> CH_SHIFT). Self-loop counted in init, inserted in scanC2.
__global__ void init_deg2(int* __restrict__ deg2, int N2, int NC, int N, int hoff) {
    int i = blockIdx.x * blockDim.x + threadIdx.x;
    if (i >= N2) return;
    int r = i < N ? i : i + hoff;
    int sc = r >> CH_SHIFT;
    int base = i * NC;
    for (int k = 0; k < NC; ++k) deg2[base + k] = (k == sc) ? 1 : 0;
}

__global__ void csr_count2(const int* __restrict__ adj, const int* __restrict__ wadj,
                           int E, int N, int NC, int hoff, int* __restrict__ deg2) {
    int i = blockIdx.x * blockDim.x + threadIdx.x;
    if (i < 2 * E) {
        int s, d;
        if (i < E) {
            s = adj[i];
            d = adj[E + i];
        } else {
            s = wadj[i - E] + N;
            d = wadj[E + (i - E)] + N;
        }
        int r = s < N ? s : s + hoff;
        atomicAdd(&deg2[d * NC + (r >> CH_SHIFT)], 1);
    }
}

__global__ __launch_bounds__(256) void scanA(const int* __restrict__ deg, int* __restrict__ off,
                                             int* __restrict__ bsum, int n) {
    __shared__ int wsum[4];
    int tid = threadIdx.x, lane = tid & 63, wid = tid >> 6;
    int i = blockIdx.x * 256 + tid;
    int d = (i < n) ? deg[i] : 0;
    int x = d;
#pragma unroll
    for (int o = 1; o < 64; o <<= 1) {
        int y = __shfl_up(x, (unsigned)o, 64);
        if (lane >= o) x += y;
    }
    if (lane == 63) wsum[wid] = x;
    __syncthreads();
    int woff = 0;
    for (int j = 0; j < wid; ++j) woff += wsum[j];
    if (i < n) off[i] = woff + x - d;
    if (tid == 255) bsum[blockIdx.x] = woff + x;
}

// single-block looped scan over block sums (nb can exceed 256)
__global__ __launch_bounds__(256) void scanB_loop(const int* __restrict__ bsum,
                                                  int* __restrict__ bbase, int nb,
                                                  int* __restrict__ off2, int nseg) {
    __shared__ int wsum[4];
    __shared__ int s_run;
    int tid = threadIdx.x, lane = tid & 63, wid = tid >> 6;
    if (tid == 0) s_run = 0;
    __syncthreads();
    int nloop = (nb + 255) / 256;
    for (int c2 = 0; c2 < nloop; ++c2) {
        int i = c2 * 256 + tid;
        int d = (i < nb) ? bsum[i] : 0;
        int x = d;
#pragma unroll
        for (int o = 1; o < 64; o <<= 1) {
            int y = __shfl_up(x, (unsigned)o, 64);
            if (lane >= o) x += y;
        }
        if (lane == 63) wsum[wid] = x;
        __syncthreads();
        int woff = 0;
        for (int j = 0; j < wid; ++j) woff += wsum[j];
        int run = s_run;
        if (i < nb) bbase[i] = run + woff + x - d;
        int total = wsum[0] + wsum[1] + wsum[2] + wsum[3];
        __syncthreads();
        if (tid == 0) s_run = run + total;
        __syncthreads();
    }
    if (tid == 0) off2[nseg] = s_run;
}

// finalize seg offsets, insert self-loop at start of its (dst, chunk(dst)) segment
__global__ void scanC2(int* __restrict__ off2, const int* __restrict__ bbase,
                       int* __restrict__ cursor2, int* __restrict__ csrc,
                       int nseg, int NC, int N, int hoff) {
    int j = blockIdx.x * blockDim.x + threadIdx.x;
    if (j >= nseg) return;
    int o = off2[j] + bbase[j >> 8];
    off2[j] = o;
    int node = j / NC;
    int k = j - node * NC;
    int r = node < N ? node : node + hoff;
    int self = ((r >> CH_SHIFT) == k) ? 1 : 0;
    cursor2[j] = o + self;
    if (self) csrc[o] = node;
}

__global__ void csr_scatter2(const int* __restrict__ adj, const int* __restrict__ wadj,
                             int E, int N, int NC, int hoff,
                             int* __restrict__ cursor2, int* __restrict__ csrc) {
    int i = blockIdx.x * blockDim.x + threadIdx.x;
    if (i < 2 * E) {
        int s, d;
        if (i < E) {
            s = adj[i];
            d = adj[E + i];
        } else {
            s = wadj[i - E] + N;
            d = wadj[E + (i - E)] + N;
        }
        int r = s < N ? s : s + hoff;
        int p = atomicAdd(&cursor2[d * NC + (r >> CH_SHIFT)], 1);
        csrc[p] = s;
    }
}

// ---------------- fused softmax + gather, wave-per-dst, 8 ch/lane ----------------
__device__ __forceinline__ void edge_acc(int s, float ad, int head, int N, int hoff,
                                         const float* __restrict__ asrc,
                                         const unsigned char* __restrict__ h8, int c,
                                         float* acc, float& dsum) {
    float e = asrc[(s << 2) + head] + ad;
    e = fmaxf(e, 0.2f * e);
    float ex = __expf(e);
    dsum += ex;
    int r = s < N ? s : s + hoff;
    int2 hv = *(const int2*)(h8 + (((size_t)r) << 9) + c);
    f32x2 f01 = __builtin_amdgcn_cvt_pk_f32_fp8(hv.x, false);
    f32x2 f23 = __builtin_amdgcn_cvt_pk_f32_fp8(hv.x, true);
    f32x2 f45 = __builtin_amdgcn_cvt_pk_f32_fp8(hv.y, false);
    f32x2 f67 = __builtin_amdgcn_cvt_pk_f32_fp8(hv.y, true);
    acc[0] += ex * f01.x; acc[1] += ex * f01.y;
    acc[2] += ex * f23.x; acc[3] += ex * f23.y;
    acc[4] += ex * f45.x; acc[5] += ex * f45.y;
    acc[6] += ex * f67.x; acc[7] += ex * f67.y;
}

__global__ __launch_bounds__(256) void gat_aggregate5(
    const unsigned char* __restrict__ h8, const float* __restrict__ asrc,
    const float* __restrict__ adst, const int* __restrict__ off2, const int* __restrict__ csrc,
    const float* __restrict__ bias, float* __restrict__ partAB, int N, int Mpad, int NC) {
    __shared__ float spool[1024];
    int tid = threadIdx.x;
    for (int i = tid; i < 1024; i += 256) spool[i] = 0.f;
    __syncthreads();
    int wv = tid >> 6, l = tid & 63;
    int c = l << 3;
    int head = l >> 4;
    float bb[8];
#pragma unroll
    for (int k = 0; k < 8; ++k) bb[k] = bias[c + k];
    float poolA[8] = {0.f, 0.f, 0.f, 0.f, 0.f, 0.f, 0.f, 0.f};
    float poolB[8] = {0.f, 0.f, 0.f, 0.f, 0.f, 0.f, 0.f, 0.f};
    const int N2 = 2 * N, hoff = Mpad - N;
    const int stride = gridDim.x << 2;
    for (int dst = (blockIdx.x << 2) + wv; dst < N2; dst += stride) {
        int segbase = dst * NC;
        int p0 = off2[segbase], p1 = off2[segbase + NC];
        float ad = adst[(dst << 2) + head];
        float acc[8] = {0.f, 0.f, 0.f, 0.f, 0.f, 0.f, 0.f, 0.f};
        float dsum = 0.f;
        int p = p0;
        for (; p + 4 <= p1; p += 4) {
            int4 sv = *(const int4*)(csrc + p);
            edge_acc(sv.x, ad, head, N, hoff, asrc, h8, c, acc, dsum);
            edge_acc(sv.y, ad, head, N, hoff, asrc, h8, c, acc, dsum);
            edge_acc(sv.z, ad, head, N, hoff, asrc, h8, c, acc, dsum);
            edge_acc(sv.w, ad, head, N, hoff, asrc, h8, c, acc, dsum);
        }
        for (; p < p1; ++p)
            edge_acc(csrc[p], ad, head, N, hoff, asrc, h8, c, acc, dsum);
        float inv = 1.f / (dsum + 1e-16f);
        if (dst < N) {
#pragma unroll
            for (int k = 0; k < 8; ++k) {
                float o = acc[k] * inv + bb[k];
                poolA[k] += fmaxf(o, 0.01f * o);
            }
        } else {
#pragma unroll
            for (int k = 0; k < 8; ++k) {
                float o = acc[k] * inv + bb[k];
                poolB[k] += fmaxf(o, 0.01f * o);
            }
        }
    }
#pragma unroll
    for (int k = 0; k < 8; ++k) {
        atomicAdd(&spool[c + k], poolA[k]);
        atomicAdd(&spool[512 + c + k], poolB[k]);
    }
    __syncthreads();
    int base = (blockIdx.x & 63) << 9;
    for (int i = tid; i < 1024; i += 256) {
        float* dp = (i < 512) ? (partAB + base + i) : (partAB + 64 * 512 + base + (i - 512));
        atomicAdd(dp, spool[i]);
    }
}

// ---------------- fused mean-pool reduce + fc + concat ----------------
__global__ __launch_bounds__(256) void fc_final2(
    const float* __restrict__ partAB, const float* __restrict__ w, const float* __restrict__ b,
    float* __restrict__ out, float invN) {
    __shared__ float gA[512], gB[512];
    __shared__ float rA[256], rB[256];
    int t = threadIdx.x;
    for (int i = t; i < 512; i += 256) {
        float sA = 0.f, sB = 0.f;
        for (int r = 0; r < 64; ++r) {
            sA += partAB[r * 512 + i];
            sB += partAB[64 * 512 + r * 512 + i];
        }
        gA[i] = sA * invN;
        gB[i] = sB * invN;
    }
    __syncthreads();
    int jj = t & 31, ks = t >> 5;
    int j = blockIdx.x * 32 + jj;
    float sA = 0.f, sB = 0.f;
    for (int k = ks * 64; k < ks * 64 + 64; ++k) {
        float wv = w[k * 512 + j];
        sA += gA[k] * wv;
        sB += gB[k] * wv;
    }
    rA[t] = sA;
    rB[t] = sB;
    __syncthreads();
    if (ks == 0) {
#pragma unroll
        for (int s2 = 1; s2 < 8; ++s2) {
            sA += rA[jj + 32 * s2];
            sB += rB[jj + 32 * s2];
        }
        sA += b[j];
        sB += b[j];
        sA = sA >= 0.f ? sA : 0.01f * sA;
        sB = sB >= 0.f ? sB : 0.01f * sB;
        out[j] = sA;
        out[512 + j] = sB;
        out[1024 + j] = sA - sB;
    }
}

// ---------------- launch ----------------
extern "C" void kernel_launch(void* const* d_in, const int* in_sizes, int n_in,
                              void* d_out, int out_size, void* d_ws, size_t ws_size,
                              hipStream_t stream) {
    const float* x = (const float*)d_in[0];
    const int* adj = (const int*)d_in[1];
    const float* wtx = (const float*)d_in[2];
    const int* wadj = (const int*)d_in[3];
    const float* W = (const float*)d_in[4];
    const float* att_s = (const float*)d_in[5];
    const float* att_d = (const float*)d_in[6];
    const float* bias = (const float*)d_in[7];
    const float* fc1w = (const float*)d_in[8];
    const float* fc1b = (const float*)d_in[9];
    float* out = (float*)d_out;

    const int N = in_sizes[0] / 512;  // 20000
    const int E = in_sizes[1] / 2;    // 320000
    const int Mpad = ((N + 127) / 128) * 128;
    const int N2 = 2 * N;
    const int hoff = Mpad - N;
    const int NC = (2 * Mpad + (1 << CH_SHIFT) - 1) >> CH_SHIFT;  // src chunks (10)
    const int nseg = N2 * NC;
    const int nbA = (nseg + 255) / 256;

    char* p = (char*)d_ws;
    auto alloc = [&](size_t bytes) -> char* {
        char* r = p;
        p += (bytes + 255) & ~(size_t)255;
        return r;
    };
    u16* xb = (u16*)alloc((size_t)2 * Mpad * 512 * 2);
    unsigned char* h8 = (unsigned char*)alloc((size_t)2 * Mpad * 512);
    u16* Wt = (u16*)alloc(512 * 512 * 2);
    float* asrc = (float*)alloc((size_t)N2 * 4 * 4);
    float* adst = (float*)alloc((size_t)N2 * 4 * 4);
    int* deg2 = (int*)alloc((size_t)nseg * 4);
    int* off2 = (int*)alloc((size_t)(nseg + 1) * 4);
    int* cursor2 = (int*)alloc((size_t)nseg * 4);
    int* bsum = (int*)alloc((size_t)(nbA + 1) * 4);
    int* bbase = (int*)alloc((size_t)(nbA + 1) * 4);
    int* csrc = (int*)alloc((size_t)2 * (E + N) * 4);
    float* partAB = (float*)alloc((size_t)2 * 64 * 512 * 4);

    hipMemsetAsync(partAB, 0, (size_t)2 * 64 * 512 * 4, stream);
    cast_wt_kernel<<<(512 * 512) / 256, 256, 0, stream>>>(W, Wt);

    size_t total4 = (size_t)2 * Mpad * 512 / 4;
    cast_x_all<<<(int)((total4 + 255) / 256), 256, 0, stream>>>(x, wtx, xb, N, Mpad);

    // 2-level CSR build (independent of GEMM)
    init_deg2<<<(N2 + 255) / 256, 256, 0, stream>>>(deg2, N2, NC, N, hoff);
    csr_count2<<<(2 * E + 255) / 256, 256, 0, stream>>>(adj, wadj, E, N, NC, hoff, deg2);
    scanA<<<nbA, 256, 0, stream>>>(deg2, off2, bsum, nseg);
    scanB_loop<<<1, 256, 0, stream>>>(bsum, bbase, nbA, off2, nseg);
    scanC2<<<nbA, 256, 0, stream>>>(off2, bbase, cursor2, csrc, nseg, NC, N, hoff);
    csr_scatter2<<<(2 * E + 255) / 256, 256, 0, stream>>>(adj, wadj, E, N, NC, hoff, cursor2, csrc);

    // fused GEMM: writes h8 + attention logits (head index fastest -> A reuse)
    dim3 gg(4, 2 * Mpad / 128, 1);
    gemm_fused<<<gg, 256, 0, stream>>>(xb, Wt, h8, att_s, att_d, asrc, adst, N, Mpad);

    gat_aggregate5<<<2048, 256, 0, stream>>>(h8, asrc, adst, off2, csrc, bias, partAB,
                                             N, Mpad, NC);

    fc_final2<<<16, 256, 0, stream>>>(partAB, fc1w, fc1b, out, 1.0f / (float)N);
}

// Round 8
// 354.089 us; speedup vs baseline: 1.1451x; 1.0011x over previous
//
#include <hip/hip_runtime.h>
#include <hip/hip_bf16.h>

typedef unsigned short u16;
typedef short bf16x8 __attribute__((ext_vector_type(8)));
typedef float f32x4 __attribute__((ext_vector_type(4)));
typedef float f32x2 __attribute__((ext_vector_type(2)));

__device__ __forceinline__ u16 f2b(float f) {
    unsigned x = __float_as_uint(f);
    return (u16)((x + 0x7fffu + ((x >> 16) & 1u)) >> 16);
}

// pack two f32 to bf16x2 by truncation: one v_perm_b32
__device__ __forceinline__ int pkbf(float lo, float hi) {
    return __builtin_amdgcn_perm(__float_as_uint(hi), __float_as_uint(lo), 0x07060302);
}

__global__ void cast_wt_kernel(const float* __restrict__ W, u16* __restrict__ Wt) {
    int idx = blockIdx.x * blockDim.x + threadIdx.x;  // 512*512
    int n = idx >> 9, k = idx & 511;
    Wt[idx] = f2b(W[k * 512 + n]);
}

// ---------------- GEMM fused: f32 A staging + h8 (fp8) + attention logits ----------------
// grid (4 heads fastest, 2*Mpad/128 row tiles). A read straight from x/wtx (f32),
// truncated to bf16 at LDS->reg. asrc/adst indexed by hrow.
__global__ __launch_bounds__(256, 2) void gemm_fused2(
    const float* __restrict__ xA, const float* __restrict__ xW, const u16* __restrict__ Bt,
    unsigned char* __restrict__ h8, const float* __restrict__ att_src,
    const float* __restrict__ att_dst, float* __restrict__ asrc, float* __restrict__ adst,
    int N, int Mpad) {
    __shared__ float lA[128 * 32];
    __shared__ u16 lB[128 * 32];
    __shared__ float sred[2][128][2];
    const int tid = threadIdx.x;
    const int w = tid >> 6, l = tid & 63;
    const int row0 = blockIdx.y * 128;
    const int head = blockIdx.x;
    const int col0 = head * 128;
    const int wr = w >> 1, wc = w & 1;
    const int mlane = l & 15, quad = l >> 4;

    const float* src = (row0 >= Mpad) ? xW : xA;
    const int rbase = row0 - (row0 >= Mpad ? Mpad : 0);
    // A staging: lane covers row (g*32 + w*8 + l/8), floats (l&7)*4
    const int arow = (w << 3) + (l >> 3);
    const int acol = (l & 7) << 2;
    // B staging: as before (bf16)
    const int srow = (w << 4) + (l >> 2);
    const int scol = (l & 3) << 3;

    f32x4 acc[4][4];
#pragma unroll
    for (int i = 0; i < 4; i++)
#pragma unroll
        for (int j = 0; j < 4; j++) acc[i][j] = f32x4{0.f, 0.f, 0.f, 0.f};

    for (int k0 = 0; k0 < 512; k0 += 32) {
#pragma unroll
        for (int g = 0; g < 4; ++g) {
            int lrow = rbase + g * 32 + arow;
            lrow = min(lrow, N - 1);  // pad rows: clamp (results are don't-care)
            const float* ga = src + (size_t)lrow * 512 + k0 + acol;
            float* la = lA + (g * 32 + (w << 3)) * 32;  // wave-uniform base
            __builtin_amdgcn_global_load_lds((const __attribute__((address_space(1))) void*)ga,
                                             (__attribute__((address_space(3))) void*)la, 16, 0, 0);
        }
#pragma unroll
        for (int s = 0; s < 2; ++s) {
            const u16* gb = Bt + (size_t)(col0 + s * 64 + srow) * 512 + (k0 + scol);
            u16* lb = lB + s * 2048 + w * 512;
            __builtin_amdgcn_global_load_lds((const __attribute__((address_space(1))) void*)gb,
                                             (__attribute__((address_space(3))) void*)lb, 16, 0, 0);
        }
        __syncthreads();
        bf16x8 af[4], bfr[4];
#pragma unroll
        for (int i = 0; i < 4; i++) {
            const float* ap = &lA[(wr * 64 + i * 16 + mlane) * 32 + quad * 8];
            float4 f0 = *(const float4*)ap;
            float4 f1 = *(const float4*)(ap + 4);
            int* ai = (int*)&af[i];
            ai[0] = pkbf(f0.x, f0.y);
            ai[1] = pkbf(f0.z, f0.w);
            ai[2] = pkbf(f1.x, f1.y);
            ai[3] = pkbf(f1.z, f1.w);
            bfr[i] = *(const bf16x8*)&lB[(wc * 64 + i * 16 + mlane) * 32 + quad * 8];
        }
#pragma unroll
        for (int i = 0; i < 4; i++)
#pragma unroll
            for (int j = 0; j < 4; j++)
                acc[i][j] = __builtin_amdgcn_mfma_f32_16x16x32_bf16(af[i], bfr[j], acc[i][j], 0, 0, 0);
        __syncthreads();
    }

    float as_j[4], ad_j[4];
#pragma unroll
    for (int j = 0; j < 4; j++) {
        as_j[j] = att_src[col0 + wc * 64 + j * 16 + mlane];
        ad_j[j] = att_dst[col0 + wc * 64 + j * 16 + mlane];
    }
#pragma unroll
    for (int i = 0; i < 4; i++) {
#pragma unroll
        for (int r = 0; r < 4; r++) {
            float vs = 0.f, vd = 0.f;
#pragma unroll
            for (int j = 0; j < 4; j++) {
                float hv = acc[i][j][r];
                vs += hv * as_j[j];
                vd += hv * ad_j[j];
            }
#pragma unroll
            for (int o = 8; o >= 1; o >>= 1) {
                vs += __shfl_xor(vs, o);
                vd += __shfl_xor(vd, o);
            }
            if (mlane == 0) {
                int lrow = wr * 64 + i * 16 + quad * 4 + r;
                sred[0][lrow][wc] = vs;
                sred[1][lrow][wc] = vd;
            }
        }
    }
#pragma unroll
    for (int i = 0; i < 4; i++)
#pragma unroll
        for (int j = 0; j < 4; j++)
#pragma unroll
            for (int r = 0; r < 4; r++) {
                int rg = row0 + wr * 64 + i * 16 + quad * 4 + r;
                int cg = col0 + wc * 64 + j * 16 + mlane;
                float v = acc[i][j][r];
                unsigned pk = __builtin_amdgcn_cvt_pk_fp8_f32(v, v, 0, false);
                h8[(size_t)rg * 512 + cg] = (unsigned char)(pk & 0xff);
            }
    __syncthreads();
    {
        int row = tid & 127, which = tid >> 7;
        int rg = row0 + row;  // hrow
        float v = sred[which][row][0] + sred[which][row][1];
        (which ? adst : asrc)[(rg << 2) + head] = v;
    }
}

// ---------------- CSR over hrow space [0, 2*Mpad) ----------------
__global__ void csr_count(const int* __restrict__ adj, const int* __restrict__ wadj,
                          int E, int Mpad, int* __restrict__ deg) {
    int i = blockIdx.x * blockDim.x + threadIdx.x;
    if (i < 2 * E) {
        int d = (i < E) ? adj[E + i] : (wadj[E + (i - E)] + Mpad);
        atomicAdd(&deg[d], 1);
    }
}

// scanA over n=2*Mpad rows; +1 self-loop for valid (non-pad) rows
__global__ __launch_bounds__(256) void scanA(const int* __restrict__ deg, int* __restrict__ off,
                                             int* __restrict__ bsum, int n, int N, int Mpad) {
    __shared__ int wsum[4];
    int tid = threadIdx.x, lane = tid & 63, wid = tid >> 6;
    int i = blockIdx.x * 256 + tid;
    int valid = (i < N) || (i >= Mpad && i < Mpad + N);
    int d = (i < n) ? deg[i] + (valid ? 1 : 0) : 0;
    int x = d;
#pragma unroll
    for (int o = 1; o < 64; o <<= 1) {
        int y = __shfl_up(x, (unsigned)o, 64);
        if (lane >= o) x += y;
    }
    if (lane == 63) wsum[wid] = x;
    __syncthreads();
    int woff = 0;
    for (int j = 0; j < wid; ++j) woff += wsum[j];
    if (i < n) off[i] = woff + x - d;
    if (tid == 255) bsum[blockIdx.x] = woff + x;
}

__global__ __launch_bounds__(256) void scanB(const int* __restrict__ bsum, int* __restrict__ bbase,
                                             int nb, int* __restrict__ off, int n) {
    __shared__ int wsum[4];
    int tid = threadIdx.x, lane = tid & 63, wid = tid >> 6;
    int d = (tid < nb) ? bsum[tid] : 0;
    int x = d;
#pragma unroll
    for (int o = 1; o < 64; o <<= 1) {
        int y = __shfl_up(x, (unsigned)o, 64);
        if (lane >= o) x += y;
    }
    if (lane == 63) wsum[wid] = x;
    __syncthreads();
    int woff = 0;
    for (int j = 0; j < wid; ++j) woff += wsum[j];
    int excl = woff + x - d;
    if (tid < nb) bbase[tid] = excl;
    if (tid == nb - 1) off[n] = excl + d;
}

__global__ void scanC(int* __restrict__ off, const int* __restrict__ bbase,
                      int* __restrict__ cursor, int* __restrict__ csrc, int n, int N, int Mpad) {
    int i = blockIdx.x * blockDim.x + threadIdx.x;
    if (i < n) {
        int o = off[i] + bbase[i >> 8];
        off[i] = o;
        int valid = (i < N) || (i >= Mpad && i < Mpad + N);
        if (valid) csrc[o] = i;  // self loop (hrow)
        cursor[i] = o + valid;
    }
}

__global__ void csr_scatter(const int* __restrict__ adj, const int* __restrict__ wadj,
                            int E, int Mpad, int* __restrict__ cursor, int* __restrict__ csrc) {
    int i = blockIdx.x * blockDim.x + threadIdx.x;
    if (i < 2 * E) {
        int s, d;
        if (i < E) {
            s = adj[i];
            d = adj[E + i];
        } else {
            s = wadj[i - E] + Mpad;
            d = wadj[E + (i - E)] + Mpad;
        }
        int p = atomicAdd(&cursor[d], 1);
        csrc[p] = s;
    }
}

// ---------------- fused softmax + gather: wave per dst-PAIR (2x MLP), 8 ch/lane ----------------
__device__ __forceinline__ void edge2(int hr, float ad, int head, const float* __restrict__ asrc,
                                      const unsigned char* __restrict__ h8, int c,
                                      float* acc, float& dsum) {
    float e = asrc[(hr << 2) + head] + ad;
    e = fmaxf(e, 0.2f * e);
    float ex = __expf(e);
    dsum += ex;
    int2 hv = *(const int2*)(h8 + (((size_t)hr) << 9) + c);
    f32x2 f01 = __builtin_amdgcn_cvt_pk_f32_fp8(hv.x, false);
    f32x2 f23 = __builtin_amdgcn_cvt_pk_f32_fp8(hv.x, true);
    f32x2 f45 = __builtin_amdgcn_cvt_pk_f32_fp8(hv.y, false);
    f32x2 f67 = __builtin_amdgcn_cvt_pk_f32_fp8(hv.y, true);
    acc[0] += ex * f01.x; acc[1] += ex * f01.y;
    acc[2] += ex * f23.x; acc[3] += ex * f23.y;
    acc[4] += ex * f45.x; acc[5] += ex * f45.y;
    acc[6] += ex * f67.x; acc[7] += ex * f67.y;
}

__global__ __launch_bounds__(256) void gat_aggregate6(
    const unsigned char* __restrict__ h8, const float* __restrict__ asrc,
    const float* __restrict__ adst, const int* __restrict__ off, const int* __restrict__ csrc,
    const float* __restrict__ bias, float* __restrict__ partAB, int Mpad) {
    __shared__ float spool[1024];
    int tid = threadIdx.x;
    for (int i = tid; i < 1024; i += 256) spool[i] = 0.f;
    __syncthreads();
    int wv = tid >> 6, l = tid & 63;
    int c = l << 3;
    int head = l >> 4;
    float bb[8];
#pragma unroll
    for (int k = 0; k < 8; ++k) bb[k] = bias[c + k];
    float poolA[8] = {0.f, 0.f, 0.f, 0.f, 0.f, 0.f, 0.f, 0.f};
    float poolB[8] = {0.f, 0.f, 0.f, 0.f, 0.f, 0.f, 0.f, 0.f};
    const int npairs = Mpad;  // 2*Mpad rows / 2
    const int stride = gridDim.x << 2;
    for (int pr = (blockIdx.x << 2) + wv; pr < npairs; pr += stride) {
        int d0 = pr << 1, d1 = d0 + 1;
        int q0 = off[d0], q1 = off[d0 + 1], q2 = off[d0 + 2];
        int n0 = q1 - q0, n1 = q2 - q1;
        float ad0 = adst[(d0 << 2) + head];
        float ad1 = adst[(d1 << 2) + head];
        float acc0[8] = {0.f, 0.f, 0.f, 0.f, 0.f, 0.f, 0.f, 0.f};
        float acc1[8] = {0.f, 0.f, 0.f, 0.f, 0.f, 0.f, 0.f, 0.f};
        float dsum0 = 0.f, dsum1 = 0.f;
        int m = n0 < n1 ? n0 : n1;
        int i = 0;
        for (; i + 2 <= m; i += 2) {
            int2 ca = *(const int2*)(csrc + q0 + i);
            int2 cb = *(const int2*)(csrc + q1 + i);
            edge2(ca.x, ad0, head, asrc, h8, c, acc0, dsum0);
            edge2(cb.x, ad1, head, asrc, h8, c, acc1, dsum1);
            edge2(ca.y, ad0, head, asrc, h8, c, acc0, dsum0);
            edge2(cb.y, ad1, head, asrc, h8, c, acc1, dsum1);
        }
        for (int j = i; j < n0; ++j) edge2(csrc[q0 + j], ad0, head, asrc, h8, c, acc0, dsum0);
        for (int j = i; j < n1; ++j) edge2(csrc[q1 + j], ad1, head, asrc, h8, c, acc1, dsum1);
        bool isB = d0 >= Mpad;
        float* pool = isB ? poolB : poolA;
        if (n0 > 0) {
            float inv = 1.f / (dsum0 + 1e-16f);
#pragma unroll
            for (int k = 0; k < 8; ++k) {
                float o = acc0[k] * inv + bb[k];
                pool[k] += fmaxf(o, 0.01f * o);
            }
        }
        if (n1 > 0) {
            float inv = 1.f / (dsum1 + 1e-16f);
#pragma unroll
            for (int k = 0; k < 8; ++k) {
                float o = acc1[k] * inv + bb[k];
                pool[k] += fmaxf(o, 0.01f * o);
            }
        }
    }
#pragma unroll
    for (int k = 0; k < 8; ++k) {
        atomicAdd(&spool[c + k], poolA[k]);
        atomicAdd(&spool[512 + c + k], poolB[k]);
    }
    __syncthreads();
    int base = (blockIdx.x & 63) << 9;
    for (int i = tid; i < 1024; i += 256) {
        float* dp = (i < 512) ? (partAB + base + i) : (partAB + 64 * 512 + base + (i - 512));
        atomicAdd(dp, spool[i]);
    }
}

// ---------------- fused mean-pool reduce + fc + concat ----------------
__global__ __launch_bounds__(256) void fc_final2(
    const float* __restrict__ partAB, const float* __restrict__ w, const float* __restrict__ b,
    float* __restrict__ out, float invN) {
    __shared__ float gA[512], gB[512];
    __shared__ float rA[256], rB[256];
    int t = threadIdx.x;
    for (int i = t; i < 512; i += 256) {
        float sA = 0.f, sB = 0.f;
        for (int r = 0; r < 64; ++r) {
            sA += partAB[r * 512 + i];
            sB += partAB[64 * 512 + r * 512 + i];
        }
        gA[i] = sA * invN;
        gB[i] = sB * invN;
    }
    __syncthreads();
    int jj = t & 31, ks = t >> 5;
    int j = blockIdx.x * 32 + jj;
    float sA = 0.f, sB = 0.f;
    for (int k = ks * 64; k < ks * 64 + 64; ++k) {
        float wv = w[k * 512 + j];
        sA += gA[k] * wv;
        sB += gB[k] * wv;
    }
    rA[t] = sA;
    rB[t] = sB;
    __syncthreads();
    if (ks == 0) {
#pragma unroll
        for (int s2 = 1; s2 < 8; ++s2) {
            sA += rA[jj + 32 * s2];
            sB += rB[jj + 32 * s2];
        }
        sA += b[j];
        sB += b[j];
        sA = sA >= 0.f ? sA : 0.01f * sA;
        sB = sB >= 0.f ? sB : 0.01f * sB;
        out[j] = sA;
        out[512 + j] = sB;
        out[1024 + j] = sA - sB;
    }
}

// ---------------- launch ----------------
extern "C" void kernel_launch(void* const* d_in, const int* in_sizes, int n_in,
                              void* d_out, int out_size, void* d_ws, size_t ws_size,
                              hipStream_t stream) {
    const float* x = (const float*)d_in[0];
    const int* adj = (const int*)d_in[1];
    const float* wtx = (const float*)d_in[2];
    const int* wadj = (const int*)d_in[3];
    const float* W = (const float*)d_in[4];
    const float* att_s = (const float*)d_in[5];
    const float* att_d = (const float*)d_in[6];
    const float* bias = (const float*)d_in[7];
    const float* fc1w = (const float*)d_in[8];
    const float* fc1b = (const float*)d_in[9];
    float* out = (float*)d_out;

    const int N = in_sizes[0] / 512;  // 20000
    const int E = in_sizes[1] / 2;    // 320000
    const int Mpad = ((N + 127) / 128) * 128;
    const int R2 = 2 * Mpad;          // hrow space
    const int nb = (R2 + 255) / 256;  // 157

    char* p = (char*)d_ws;
    auto alloc = [&](size_t bytes) -> char* {
        char* r = p;
        p += (bytes + 255) & ~(size_t)255;
        return r;
    };
    unsigned char* h8 = (unsigned char*)alloc((size_t)R2 * 512);
    u16* Wt = (u16*)alloc(512 * 512 * 2);
    float* asrc = (float*)alloc((size_t)R2 * 4 * 4);
    float* adst = (float*)alloc((size_t)R2 * 4 * 4);
    int* deg = (int*)alloc((size_t)R2 * 4);
    int* off = (int*)alloc((size_t)(R2 + 1) * 4);
    int* cursor = (int*)alloc((size_t)R2 * 4);
    int* bsum = (int*)alloc(256 * 4);
    int* bbase = (int*)alloc(256 * 4);
    int* csrc = (int*)alloc((size_t)2 * (E + N) * 4);
    float* partAB = (float*)alloc((size_t)2 * 64 * 512 * 4);

    hipMemsetAsync(partAB, 0, (size_t)2 * 64 * 512 * 4, stream);
    hipMemsetAsync(deg, 0, (size_t)R2 * 4, stream);
    cast_wt_kernel<<<(512 * 512) / 256, 256, 0, stream>>>(W, Wt);

    // CSR build (independent of GEMM)
    csr_count<<<(2 * E + 255) / 256, 256, 0, stream>>>(adj, wadj, E, Mpad, deg);
    scanA<<<nb, 256, 0, stream>>>(deg, off, bsum, R2, N, Mpad);
    scanB<<<1, 256, 0, stream>>>(bsum, bbase, nb, off, R2);
    scanC<<<nb, 256, 0, stream>>>(off, bbase, cursor, csrc, R2, N, Mpad);
    csr_scatter<<<(2 * E + 255) / 256, 256, 0, stream>>>(adj, wadj, E, Mpad, cursor, csrc);

    // fused GEMM from f32 inputs (head fastest -> A-stripe reuse)
    dim3 gg(4, R2 / 128, 1);
    gemm_fused2<<<gg, 256, 0, stream>>>(x, wtx, Wt, h8, att_s, att_d, asrc, adst, N, Mpad);

    gat_aggregate6<<<2048, 256, 0, stream>>>(h8, asrc, adst, off, csrc, bias, partAB, Mpad);

    fc_final2<<<16, 256, 0, stream>>>(partAB, fc1w, fc1b, out, 1.0f / (float)N);
}